// Round 1
// baseline (222.603 us; speedup 1.0000x reference)
//
#include <hip/hip_runtime.h>
#include <math.h>

#define DIM 1024
#define NPAIRS 512   // DIM/2
#define NLEVELS 9    // l = 1..9 (l=0 is skipped in the reference)

// ---------------------------------------------------------------------------
// Kernel 1: collapse the 9 butterfly levels into one complex weight per pair.
// Each level l applies z <- (a - i b) * z to z = u[2p] + i*u[2p+1], with
// (a,b) shared per block of size 2^l. Composite weight is row-independent.
// ---------------------------------------------------------------------------
__global__ void butterfly_weights_kernel(const float* __restrict__ params,
                                         float2* __restrict__ w) {
    int p = blockIdx.x * blockDim.x + threadIdx.x;
    if (p >= NPAIRS) return;
    float wr = 1.0f, wi = 0.0f;
    int off = 2 * DIM;  // first 2048 params belong to l=0, which is a no-op
#pragma unroll
    for (int l = 1; l <= NLEVELS; ++l) {
        int j = p >> (l - 1);              // block index at this level
        float a = params[off + 2 * j];
        float b = params[off + 2 * j + 1];
        // (wr + i wi) * (a - i b)
        float nr = wr * a + wi * b;
        float ni = wi * a - wr * b;
        wr = nr;
        wi = ni;
        off += 2 * (DIM >> l);
    }
    w[p] = make_float2(wr, wi);
}

// ---------------------------------------------------------------------------
// Kernel 2: one block per row. load -> ||x|| -> artanh scale -> complex mul
// by w -> ||u|| -> tanh scale -> store. 4 floats (2 pairs) per thread.
// ---------------------------------------------------------------------------
__device__ __forceinline__ float block_reduce_sum(float val, float* red) {
#pragma unroll
    for (int o = 32; o > 0; o >>= 1) val += __shfl_down(val, o);
    int lane = threadIdx.x & 63;
    int wave = threadIdx.x >> 6;
    if (lane == 0) red[wave] = val;
    __syncthreads();
    if (threadIdx.x == 0) red[4] = red[0] + red[1] + red[2] + red[3];
    __syncthreads();
    return red[4];
}

__global__ __launch_bounds__(256) void hyper_butterfly_kernel(
        const float* __restrict__ x,
        const float4* __restrict__ w4,   // (wr0, wi0, wr1, wi1) per thread
        float* __restrict__ out) {
    __shared__ float red0[8];
    __shared__ float red1[8];

    const int t = threadIdx.x;
    const size_t row = blockIdx.x;
    const float4* xrow = (const float4*)(x + row * (size_t)DIM);

    float4 v = xrow[t];

    // ---- log map at origin: u = artanh(r)/r * x,  r = ||x|| ----
    float part = v.x * v.x + v.y * v.y + v.z * v.z + v.w * v.w;
    float xn2 = block_reduce_sum(part, red0);
    float r = sqrtf(xn2);
    // artanh(r)/r ; r ~ 0.32 for this problem, guard tiny r -> limit 1
    float s1 = (r > 1e-12f) ? (0.5f * logf((1.0f + r) / (1.0f - r)) / r) : 1.0f;

    float4 u;
    u.x = s1 * v.x;
    u.y = s1 * v.y;
    u.z = s1 * v.z;
    u.w = s1 * v.w;

    // ---- butterfly: per adjacent pair, z' = (wr + i wi) * z ----
    float4 wv = w4[t];
    float4 y;
    y.x = wv.x * u.x - wv.y * u.y;
    y.y = wv.x * u.y + wv.y * u.x;
    y.z = wv.z * u.z - wv.w * u.w;
    y.w = wv.z * u.w + wv.w * u.z;

    // ---- exp map at origin: out = tanh(s)/s * y,  s = max(||y||, 1e-8) ----
    float part2 = y.x * y.x + y.y * y.y + y.z * y.z + y.w * y.w;
    float un2 = block_reduce_sum(part2, red1);
    float vn = fmaxf(sqrtf(un2), 1e-8f);
    float s2 = tanhf(vn) / vn;

    float4 o;
    o.x = s2 * y.x;
    o.y = s2 * y.y;
    o.z = s2 * y.z;
    o.w = s2 * y.w;

    float4* orow = (float4*)(out + row * (size_t)DIM);
    orow[t] = o;
}

extern "C" void kernel_launch(void* const* d_in, const int* in_sizes, int n_in,
                              void* d_out, int out_size, void* d_ws, size_t ws_size,
                              hipStream_t stream) {
    const float* x = (const float*)d_in[0];
    const float* params = (const float*)d_in[1];
    float* out = (float*)d_out;
    float2* w = (float2*)d_ws;  // 512 * 8 B = 4 KB scratch

    int rows = in_sizes[0] / DIM;

    butterfly_weights_kernel<<<1, NPAIRS, 0, stream>>>(params, w);
    hyper_butterfly_kernel<<<rows, DIM / 4, 0, stream>>>(x, (const float4*)w, out);
}